// Round 1
// baseline (363.064 us; speedup 1.0000x reference)
//
#include <hip/hip_runtime.h>

// Problem constants (B=8, S=256, F=16384, K=32)
#define N_ELEMS  33554432   // 8*256*16384
#define N4       8388608    // N_ELEMS/4
#define K_TOTAL  65536u     // 32 * 8 * 256
#define NBINS1   4096       // 12-bit coarse histogram of sortable key

// ws layout (uint32 words)
#define C_N1     (NBINS1 + 0)   // candidate list1 counter
#define C_NEGMIN (NBINS1 + 1)   // max(~key) over strictly-positive values; 0 = none
#define C_B1     (NBINS1 + 2)   // coarse cutoff bin
#define C_KABOVE (NBINS1 + 3)   // count of elements strictly above bin B1
#define C_N2     (NBINS1 + 4)   // tie-list counter
#define C_NEED   (NBINS1 + 5)   // how many to take from the tie bin
#define C_B2     (NBINS1 + 6)   // refined cutoff bin (8 bits below B1)
#define LIST1_OFF (NBINS1 + 16)
#define CAP1     262144u        // list1 capacity (expected ~48K entries)
#define CAP2     4096u          // tie-list capacity (expected ~200 entries)

// Order-preserving fp32 -> u32 map (larger float <=> larger key)
__device__ __forceinline__ unsigned keyOf(float f) {
    unsigned b = __float_as_uint(f);
    return b ^ ((unsigned)((int)b >> 31) | 0x80000000u);
}
__device__ __forceinline__ float valOf(unsigned u) {
    unsigned b = (u & 0x80000000u) ? (u ^ 0x80000000u) : ~u;
    return __uint_as_float(b);
}
__device__ __forceinline__ unsigned umaxu(unsigned a, unsigned b) { return a > b ? a : b; }

// ---------------- init: zero histogram + counters (ws is poisoned 0xAA every call)
__global__ void k_init(unsigned* __restrict__ ws) {
    int t = blockIdx.x * 256 + threadIdx.x;
    if (t < NBINS1 + 16) ws[t] = 0u;
}

// ---------------- pass 1: coarse 4096-bin histogram (LDS) over unmasked elements
__global__ __launch_bounds__(512) void k_hist(const float4* __restrict__ x,
                                              const int* __restrict__ mask,
                                              unsigned* __restrict__ ws) {
    __shared__ unsigned lh[NBINS1];     // 16 KB
    __shared__ unsigned s_wmin[8];
    for (int b = threadIdx.x; b < NBINS1; b += 512) lh[b] = 0u;
    __syncthreads();
    unsigned negmin = 0u;               // max over ~key of positive values
    const int stride = gridDim.x * 512;
    for (int i = blockIdx.x * 512 + threadIdx.x; i < N4; i += stride) {
        // 4096 float4 per token; wave-uniform branch (256-elem chunks never cross token)
        if (!mask[i >> 12]) continue;   // masked tokens never enter top-k (k << unmasked count)
        float4 v = x[i];
        float fv[4] = {v.x, v.y, v.z, v.w};
        #pragma unroll
        for (int c = 0; c < 4; c++) {
            float f = fv[c];
            unsigned u = keyOf(f);
            atomicAdd(&lh[u >> 20], 1u);
            if (f > 0.0f) negmin = umaxu(negmin, ~u);
        }
    }
    __syncthreads();
    // flush nonzero bins only (~2.5K/block) to global histogram
    for (int b = threadIdx.x; b < NBINS1; b += 512) {
        unsigned c = lh[b];
        if (c) atomicAdd(&ws[b], c);
    }
    // one global atomicMax per block for the global min-positive value
    #pragma unroll
    for (int off = 32; off > 0; off >>= 1)
        negmin = umaxu(negmin, __shfl_down(negmin, off, 64));
    int lane = threadIdx.x & 63, w = threadIdx.x >> 6;
    if (lane == 0) s_wmin[w] = negmin;
    __syncthreads();
    if (threadIdx.x == 0) {
        unsigned m = 0u;
        for (int i = 0; i < 8; i++) m = umaxu(m, s_wmin[i]);
        if (m) atomicMax(&ws[C_NEGMIN], m);
    }
}

// ---------------- suffix-scan 4096 bins -> B1, kAbove1
__global__ void k_scan1(unsigned* __restrict__ ws) {
    __shared__ unsigned sc[1024];
    const int t = threadIdx.x;
    const int BPT = NBINS1 / 1024;  // 4 bins per thread
    unsigned s = 0u;
    for (int j = 0; j < BPT; j++) s += ws[t * BPT + j];
    sc[t] = s;
    __syncthreads();
    // Hillis-Steele reverse (suffix) inclusive scan over 1024 chunk sums
    for (int off = 1; off < 1024; off <<= 1) {
        unsigned v = sc[t];
        unsigned a = (t + off < 1024) ? sc[t + off] : 0u;
        __syncthreads();
        sc[t] = v + a;
        __syncthreads();
    }
    unsigned run = (t + 1 < 1024) ? sc[t + 1] : 0u;   // cntGE(top of my chunk + 1)
    for (int j = BPT - 1; j >= 0; j--) {
        int b = t * BPT + j;
        unsigned prev = run;     // cntGE(b+1)
        run += ws[b];            // cntGE(b)
        if (run >= K_TOTAL && prev < K_TOTAL) {   // unique global crossing
            ws[C_B1] = (unsigned)b;
            ws[C_KABOVE] = prev;
        }
    }
}

// ---------------- pass 2: scatter definite winners, compact cutoff-bin candidates
#define P2_BUF 1024
__global__ __launch_bounds__(256) void k_pass2(const float4* __restrict__ x,
                                               const int* __restrict__ mask,
                                               unsigned* __restrict__ ws,
                                               float* __restrict__ out) {
    __shared__ uint2 s_buf[P2_BUF];   // block-aggregated candidate staging (8 KB)
    __shared__ unsigned s_cnt, s_base;
    if (threadIdx.x == 0) s_cnt = 0u;
    __syncthreads();
    const unsigned B1 = ws[C_B1];
    uint2* list1 = (uint2*)(ws + LIST1_OFF);
    const int stride = gridDim.x * 256;
    for (int i = blockIdx.x * 256 + threadIdx.x; i < N4; i += stride) {
        if (!mask[i >> 12]) continue;
        float4 v = x[i];
        float fv[4] = {v.x, v.y, v.z, v.w};
        #pragma unroll
        for (int c = 0; c < 4; c++) {
            float f = fv[c];
            unsigned u = keyOf(f);
            unsigned p = u >> 20;
            if (p > B1) {
                out[i * 4 + c] = fmaxf(f, 0.0f);      // definitely selected
            } else if (p == B1) {
                unsigned slot = atomicAdd(&s_cnt, 1u); // LDS atomic: cheap
                uint2 e = make_uint2(u, (unsigned)(i * 4 + c));
                if (slot < P2_BUF) s_buf[slot] = e;
                else {                                  // overflow: direct (rare)
                    unsigned g = atomicAdd(&ws[C_N1], 1u);
                    if (g < CAP1) list1[g] = e;
                }
            }
        }
    }
    __syncthreads();
    unsigned cnt = s_cnt > P2_BUF ? P2_BUF : s_cnt;
    if (threadIdx.x == 0) s_base = atomicAdd(&ws[C_N1], cnt);  // ONE atomic per block
    __syncthreads();
    for (unsigned j = threadIdx.x; j < cnt; j += 256) {
        unsigned pos = s_base + j;
        if (pos < CAP1) list1[pos] = s_buf[j];
    }
}

// ---------------- level 2a: refine candidates by next 8 bits -> B2, need
__global__ __launch_bounds__(256) void k_level2a(unsigned* __restrict__ ws) {
    __shared__ unsigned h2[256];
    uint2* list1 = (uint2*)(ws + LIST1_OFF);
    unsigned n1 = ws[C_N1]; if (n1 > CAP1) n1 = CAP1;
    int t = threadIdx.x;
    h2[t] = 0u;
    __syncthreads();
    for (unsigned i = t; i < n1; i += 256)
        atomicAdd(&h2[(list1[i].x >> 12) & 255u], 1u);
    __syncthreads();
    if (t == 0) {
        unsigned run = ws[C_KABOVE], prev = run;
        int b, found = 0;
        for (b = 255; b >= 0; b--) {
            prev = run;
            run += h2[b];
            if (run >= K_TOTAL) { found = 1; break; }
        }
        if (!found) b = 0;   // degenerate (fewer than k unmasked) — harmless
        ws[C_B2] = (unsigned)b;
        ws[C_NEED] = (K_TOTAL > prev) ? (K_TOTAL - prev) : 1u;
    }
}

// ---------------- level 2b: scatter level-2 winners, compact tie bin
__global__ __launch_bounds__(256) void k_level2b(unsigned* __restrict__ ws,
                                                 float* __restrict__ out) {
    uint2* list1 = (uint2*)(ws + LIST1_OFF);
    uint2* list2 = list1 + CAP1;
    unsigned n1 = ws[C_N1]; if (n1 > CAP1) n1 = CAP1;
    unsigned B2 = ws[C_B2];
    unsigned stride = gridDim.x * 256;
    for (unsigned i = blockIdx.x * 256 + threadIdx.x; i < n1; i += stride) {
        uint2 e = list1[i];
        unsigned bb = (e.x >> 12) & 255u;
        if (bb > B2) out[e.y] = fmaxf(valOf(e.x), 0.0f);
        else if (bb == B2) {
            unsigned g = atomicAdd(&ws[C_N2], 1u);   // ~200 total, fine
            if (g < CAP2) list2[g] = e;
        }
    }
}

// ---------------- final: exact rank in tie bin (ties -> lower index first, matching
// jax.lax.top_k stability), scatter last winners, threshold EMA
__global__ __launch_bounds__(256) void k_final(unsigned* __restrict__ ws,
                                               float* __restrict__ out,
                                               const float* __restrict__ thr) {
    __shared__ uint2 ent[4096];       // 32 KB
    __shared__ unsigned sMin[256];
    uint2* list1 = (uint2*)(ws + LIST1_OFF);
    uint2* list2 = list1 + CAP1;
    unsigned n2 = ws[C_N2]; if (n2 > CAP2) n2 = CAP2;
    unsigned need = ws[C_NEED];
    int t = threadIdx.x;
    for (unsigned i = t; i < n2; i += 256) ent[i] = list2[i];
    __syncthreads();
    unsigned minSel = 0xFFFFFFFFu;
    for (unsigned i = t; i < n2; i += 256) {
        uint2 e = ent[i];
        unsigned rank = 0u;
        for (unsigned j = 0; j < n2; j++) {
            uint2 o = ent[j];
            rank += (o.x > e.x || (o.x == e.x && o.y < e.y)) ? 1u : 0u;
        }
        if (rank < need) {
            out[e.y] = fmaxf(valOf(e.x), 0.0f);
            if (e.x < minSel) minSel = e.x;
        }
    }
    sMin[t] = minSel;
    __syncthreads();
    for (int off = 128; off > 0; off >>= 1) {
        if (t < off) sMin[t] = sMin[t] < sMin[t + off] ? sMin[t] : sMin[t + off];
        __syncthreads();
    }
    if (t == 0) {
        float thr_old = thr[0];
        float newt = thr_old;
        unsigned vku = sMin[0];   // min selected key == k-th largest value
        if (vku != 0xFFFFFFFFu) {
            float vk = valOf(vku);
            float minpos; int any;
            if (vk > 0.0f) { minpos = vk; any = 1; }   // cutoff positive -> it IS min_pos
            else {
                // cutoff <= 0: every positive element is selected -> global min positive
                unsigned nm = ws[C_NEGMIN];
                any = (nm != 0u);
                minpos = any ? valOf(~nm) : 0.0f;
            }
            if (any) newt = 0.99f * thr_old + 0.01f * minpos;
        }
        out[N_ELEMS] = newt;   // threshold output slot
    }
}

extern "C" void kernel_launch(void* const* d_in, const int* in_sizes, int n_in,
                              void* d_out, int out_size, void* d_ws, size_t ws_size,
                              hipStream_t stream) {
    const float4* x   = (const float4*)d_in[0];
    const int* mask   = (const int*)d_in[1];
    const float* thr  = (const float*)d_in[2];
    float* out        = (float*)d_out;
    unsigned* ws      = (unsigned*)d_ws;

    // zero the whole output (result + threshold slot); unselected/masked stay 0
    hipMemsetAsync(d_out, 0, (size_t)out_size * sizeof(float), stream);
    k_init  <<<(NBINS1 + 16 + 255) / 256, 256, 0, stream>>>(ws);
    k_hist  <<<512, 512, 0, stream>>>(x, mask, ws);
    k_scan1 <<<1, 1024, 0, stream>>>(ws);
    k_pass2 <<<2048, 256, 0, stream>>>(x, mask, ws, out);
    k_level2a<<<1, 256, 0, stream>>>(ws);
    k_level2b<<<64, 256, 0, stream>>>(ws, out);
    k_final <<<1, 256, 0, stream>>>(ws, out, thr);
}

// Round 2
// 289.089 us; speedup vs baseline: 1.2559x; 1.2559x over previous
//
#include <hip/hip_runtime.h>

// Problem constants (B=8, S=256, F=16384, K=32)
#define N_ELEMS   33554432   // 8*256*16384
#define N_TOKENS  2048       // B*S
#define F4        4096       // floats4 per token (F/4)
#define K_TOTAL   65536u     // K * B * S
#define NBINS1    4096       // 12-bit coarse histogram of sortable key
#define TLOW      3072       // gate bin: key>>20 >= 3072  <=>  f >= 2.0
                             // cntGE(2.0) ~ 380K >= 65536 (5.8x margin) for this input;
                             // flag-gated full-range fallback keeps exactness for any input.

// ws layout (uint32 words)
#define C_N1       (NBINS1 + 0)   // candidate list1 counter
#define C_NEGMIN   (NBINS1 + 1)   // max(~key) over strictly-positive values; 0 = none (fallback only)
#define C_B1       (NBINS1 + 2)   // coarse cutoff bin
#define C_KABOVE   (NBINS1 + 3)   // count strictly above bin B1
#define C_FALLBACK (NBINS1 + 4)   // 1 = cutoff below TLOW, full-range pass needed
#define LIST1_OFF  (NBINS1 + 16)
#define CAP1       262144u        // expected n1 ~ 54K
#define CAP2       4096u          // expected n2 ~ 210

// Order-preserving fp32 -> u32 map (larger float <=> larger key)
__device__ __forceinline__ unsigned keyOf(float f) {
    unsigned b = __float_as_uint(f);
    return b ^ ((unsigned)((int)b >> 31) | 0x80000000u);
}
__device__ __forceinline__ float valOf(unsigned u) {
    unsigned b = (u & 0x80000000u) ? (u ^ 0x80000000u) : ~u;
    return __uint_as_float(b);
}
__device__ __forceinline__ unsigned umaxu(unsigned a, unsigned b) { return a > b ? a : b; }

// ---------------- init: zero histogram + counters (ws poisoned 0xAA every call)
__global__ void k_init(unsigned* __restrict__ ws) {
    int t = blockIdx.x * 256 + threadIdx.x;
    if (t < NBINS1 + 16) ws[t] = 0u;
}

// ---------------- pass 1: gated histogram, token-major (one token per block)
__global__ __launch_bounds__(512) void k_hist(const float4* __restrict__ x,
                                              const int* __restrict__ mask,
                                              unsigned* __restrict__ ws) {
    __shared__ unsigned lh[1024];          // bins [TLOW, 4096)
    const int tok = blockIdx.x;
    if (!mask[tok]) return;                // masked token: no histogram contribution
    for (int b = threadIdx.x; b < 1024; b += 512) lh[b] = 0u;
    __syncthreads();
    const float4* xt = x + (size_t)tok * F4;
    for (int j = threadIdx.x; j < F4; j += 512) {
        float4 v = xt[j];
        float fv[4] = {v.x, v.y, v.z, v.w};
        #pragma unroll
        for (int c = 0; c < 4; c++) {
            float f = fv[c];
            if (f >= 2.0f)                 // key>>20 >= TLOW; ~2.3% of elements
                atomicAdd(&lh[(keyOf(f) >> 20) - TLOW], 1u);
        }
    }
    __syncthreads();
    for (int b = threadIdx.x; b < 1024; b += 512) {
        unsigned c = lh[b];
        if (c) atomicAdd(&ws[TLOW + b], c);   // ~30 nonzero bins/block
    }
}

// ---------------- scan1: suffix-scan bins [TLOW,4096) -> B1, kAbove (or fallback flag)
__global__ void k_scan1(unsigned* __restrict__ ws) {
    __shared__ unsigned sc[1024];
    const int t = threadIdx.x;
    sc[t] = ws[TLOW + t];
    __syncthreads();
    for (int off = 1; off < 1024; off <<= 1) {
        unsigned a = sc[t];
        unsigned b = (t + off < 1024) ? sc[t + off] : 0u;
        __syncthreads();
        sc[t] = a + b;
        __syncthreads();
    }
    unsigned run = sc[t];                             // cntGE(TLOW+t)
    unsigned prev = (t + 1 < 1024) ? sc[t + 1] : 0u;  // cntGE(TLOW+t+1)
    if (run >= K_TOTAL && prev < K_TOTAL) {
        ws[C_B1] = (unsigned)(TLOW + t);
        ws[C_KABOVE] = prev;
    }
    if (t == 0 && sc[0] < K_TOTAL) ws[C_FALLBACK] = 1u;   // cutoff below TLOW
}

// ---------------- fallback hist: full range below TLOW + negmin (gated, normally no-op)
__global__ __launch_bounds__(512) void k_hist_fb(const float4* __restrict__ x,
                                                 const int* __restrict__ mask,
                                                 unsigned* __restrict__ ws) {
    if (ws[C_FALLBACK] == 0u) return;
    __shared__ unsigned lh[TLOW];          // bins [0, TLOW): 12 KB
    __shared__ unsigned s_wmin[8];
    for (int b = threadIdx.x; b < TLOW; b += 512) lh[b] = 0u;
    __syncthreads();
    unsigned negmin = 0u;
    for (int tok = blockIdx.x; tok < N_TOKENS; tok += gridDim.x) {
        if (!mask[tok]) continue;
        const float4* xt = x + (size_t)tok * F4;
        for (int j = threadIdx.x; j < F4; j += 512) {
            float4 v = xt[j];
            float fv[4] = {v.x, v.y, v.z, v.w};
            #pragma unroll
            for (int c = 0; c < 4; c++) {
                float f = fv[c];
                unsigned u = keyOf(f);
                if ((u >> 20) < TLOW) atomicAdd(&lh[u >> 20], 1u);
                if (f > 0.0f) negmin = umaxu(negmin, ~u);
            }
        }
    }
    __syncthreads();
    for (int b = threadIdx.x; b < TLOW; b += 512) {
        unsigned c = lh[b];
        if (c) atomicAdd(&ws[b], c);
    }
    #pragma unroll
    for (int off = 32; off > 0; off >>= 1)
        negmin = umaxu(negmin, __shfl_down(negmin, off, 64));
    int lane = threadIdx.x & 63, w = threadIdx.x >> 6;
    if (lane == 0) s_wmin[w] = negmin;
    __syncthreads();
    if (threadIdx.x == 0) {
        unsigned m = 0u;
        for (int i = 0; i < 8; i++) m = umaxu(m, s_wmin[i]);
        if (m) atomicMax(&ws[C_NEGMIN], m);
    }
}

// ---------------- fallback scan: full 4096-bin suffix scan (gated, normally no-op)
__global__ void k_scan2(unsigned* __restrict__ ws) {
    if (ws[C_FALLBACK] == 0u) return;
    __shared__ unsigned sc[1024];
    const int t = threadIdx.x;
    const int BPT = NBINS1 / 1024;
    unsigned s = 0u;
    for (int j = 0; j < BPT; j++) s += ws[t * BPT + j];
    sc[t] = s;
    __syncthreads();
    for (int off = 1; off < 1024; off <<= 1) {
        unsigned a = sc[t];
        unsigned b = (t + off < 1024) ? sc[t + off] : 0u;
        __syncthreads();
        sc[t] = a + b;
        __syncthreads();
    }
    unsigned run = (t + 1 < 1024) ? sc[t + 1] : 0u;
    for (int j = BPT - 1; j >= 0; j--) {
        int b = t * BPT + j;
        unsigned prev = run;
        run += ws[b];
        if (run >= K_TOTAL && prev < K_TOTAL) {
            ws[C_B1] = (unsigned)b;
            ws[C_KABOVE] = prev;
        }
    }
    if (t == 0 && sc[0] < K_TOTAL) {       // degenerate: fewer than k candidates
        ws[C_B1] = 0u;
        ws[C_KABOVE] = sc[0] - ws[0];      // cntGE(bin 1); "need" overshoot selects all ties
    }
}

// ---------------- pass 2: dense store (zeros/winners) + compact cutoff-bin candidates
#define P2_BUF 512
__global__ __launch_bounds__(512) void k_pass2(const float4* __restrict__ x,
                                               const int* __restrict__ mask,
                                               unsigned* __restrict__ ws,
                                               float4* __restrict__ out) {
    __shared__ uint2 s_buf[P2_BUF];
    __shared__ unsigned s_cnt, s_base;
    const int tok = blockIdx.x;
    float4* ot = out + (size_t)tok * F4;
    if (!mask[tok]) {                       // masked: write zeros, no x read
        const float4 z = make_float4(0.f, 0.f, 0.f, 0.f);
        for (int j = threadIdx.x; j < F4; j += 512) ot[j] = z;
        return;
    }
    if (threadIdx.x == 0) s_cnt = 0u;
    __syncthreads();
    const unsigned B1 = ws[C_B1];
    const unsigned loKey = B1 << 20;                 // start of cutoff bin
    const unsigned hiKey = (B1 + 1u) << 20;          // start of definite winners (B1<4095 here)
    uint2* list1 = (uint2*)(ws + LIST1_OFF);
    const float4* xt = x + (size_t)tok * F4;
    for (int j = threadIdx.x; j < F4; j += 512) {
        float4 v = xt[j];
        float fv[4] = {v.x, v.y, v.z, v.w};
        float ov[4];
        #pragma unroll
        for (int c = 0; c < 4; c++) {
            float f = fv[c];
            unsigned u = keyOf(f);
            ov[c] = (u >= hiKey && B1 != 4095u) || (B1 == 4095u && (u >> 20) > 4095u)
                        ? fmaxf(f, 0.0f) : 0.0f;     // B1==4095: no definite winners
            if ((u >> 20) == B1) {                   // cutoff-bin candidate
                unsigned slot = atomicAdd(&s_cnt, 1u);
                uint2 e = make_uint2(u, (unsigned)(tok * (F4 * 4) + j * 4 + c));
                if (slot < P2_BUF) s_buf[slot] = e;
                else {
                    unsigned g = atomicAdd(&ws[C_N1], 1u);
                    if (g < CAP1) list1[g] = e;
                }
            }
        }
        ot[j] = make_float4(ov[0], ov[1], ov[2], ov[3]);
    }
    __syncthreads();
    unsigned cnt = s_cnt > P2_BUF ? P2_BUF : s_cnt;
    if (threadIdx.x == 0) s_base = atomicAdd(&ws[C_N1], cnt);   // one global atomic per block
    __syncthreads();
    for (unsigned j = threadIdx.x; j < cnt; j += 512) {
        unsigned pos = s_base + j;
        if (pos < CAP1) list1[pos] = s_buf[j];
    }
}

// ---------------- tail: refine 8 bits -> scatter level-2 winners -> exact-rank ties -> EMA
__global__ __launch_bounds__(1024) void k_tail(unsigned* __restrict__ ws,
                                               float* __restrict__ out,
                                               const float* __restrict__ thr) {
    __shared__ unsigned h2[256];
    __shared__ uint2 ent[CAP2];            // 32 KB
    __shared__ unsigned sMin[1024];
    __shared__ unsigned s_n2;
    __shared__ unsigned s_b2, s_need;
    uint2* list1 = (uint2*)(ws + LIST1_OFF);
    const int t = threadIdx.x;
    unsigned n1 = ws[C_N1]; if (n1 > CAP1) n1 = CAP1;
    // phase A: 8-bit refine histogram
    if (t < 256) h2[t] = 0u;
    if (t == 0) s_n2 = 0u;
    __syncthreads();
    for (unsigned i = t; i < n1; i += 1024)
        atomicAdd(&h2[(list1[i].x >> 12) & 255u], 1u);
    __syncthreads();
    if (t == 0) {
        unsigned run = ws[C_KABOVE], prev = run;
        int b, found = 0;
        for (b = 255; b >= 0; b--) {
            prev = run;
            run += h2[b];
            if (run >= K_TOTAL) { found = 1; break; }
        }
        if (!found) b = 0;
        s_b2 = (unsigned)b;
        s_need = (K_TOTAL > prev) ? (K_TOTAL - prev) : 1u;
    }
    __syncthreads();
    const unsigned B2 = s_b2, need = s_need;
    // phase B: scatter definite level-2 winners; collect tie bin into LDS
    for (unsigned i = t; i < n1; i += 1024) {
        uint2 e = list1[i];
        unsigned bb = (e.x >> 12) & 255u;
        if (bb > B2) out[e.y] = fmaxf(valOf(e.x), 0.0f);
        else if (bb == B2) {
            unsigned g = atomicAdd(&s_n2, 1u);
            if (g < CAP2) ent[g] = e;
        }
    }
    __syncthreads();
    unsigned n2 = s_n2 > CAP2 ? CAP2 : s_n2;
    // phase C: exact rank (ties -> lower index, matching jax.lax.top_k stability)
    unsigned minSel = 0xFFFFFFFFu;
    for (unsigned i = t; i < n2; i += 1024) {
        uint2 e = ent[i];
        unsigned rank = 0u;
        for (unsigned j = 0; j < n2; j++) {
            uint2 o = ent[j];
            rank += (o.x > e.x || (o.x == e.x && o.y < e.y)) ? 1u : 0u;
        }
        if (rank < need) {
            out[e.y] = fmaxf(valOf(e.x), 0.0f);
            if (e.x < minSel) minSel = e.x;
        }
    }
    sMin[t] = minSel;
    __syncthreads();
    for (int off = 512; off > 0; off >>= 1) {
        if (t < off) sMin[t] = sMin[t] < sMin[t + off] ? sMin[t] : sMin[t + off];
        __syncthreads();
    }
    if (t == 0) {
        float thr_old = thr[0];
        float newt = thr_old;
        unsigned vku = sMin[0];            // k-th largest value's key
        if (vku != 0xFFFFFFFFu) {
            float vk = valOf(vku);
            float minpos; int any;
            if (vk > 0.0f) { minpos = vk; any = 1; }
            else {                         // cutoff <= 0 (fallback path): global min positive
                unsigned nm = ws[C_NEGMIN];
                any = (nm != 0u);
                minpos = any ? valOf(~nm) : 0.0f;
            }
            if (any) newt = 0.99f * thr_old + 0.01f * minpos;
        }
        out[N_ELEMS] = newt;
    }
}

extern "C" void kernel_launch(void* const* d_in, const int* in_sizes, int n_in,
                              void* d_out, int out_size, void* d_ws, size_t ws_size,
                              hipStream_t stream) {
    const float4* x  = (const float4*)d_in[0];
    const int* mask  = (const int*)d_in[1];
    const float* thr = (const float*)d_in[2];
    float* out       = (float*)d_out;
    unsigned* ws     = (unsigned*)d_ws;

    k_init   <<<(NBINS1 + 16 + 255) / 256, 256, 0, stream>>>(ws);
    k_hist   <<<N_TOKENS, 512, 0, stream>>>(x, mask, ws);
    k_scan1  <<<1, 1024, 0, stream>>>(ws);
    k_hist_fb<<<512, 512, 0, stream>>>(x, mask, ws);     // gated: no-op unless fallback
    k_scan2  <<<1, 1024, 0, stream>>>(ws);               // gated: no-op unless fallback
    k_pass2  <<<N_TOKENS, 512, 0, stream>>>(x, mask, ws, (float4*)out);
    k_tail   <<<1, 1024, 0, stream>>>(ws, out, thr);
}

// Round 3
// 272.880 us; speedup vs baseline: 1.3305x; 1.0594x over previous
//
#include <hip/hip_runtime.h>

// Problem constants (B=8, S=256, F=16384, K=32)
#define N_ELEMS  33554432   // 8*256*16384
#define N4       8388608    // N_ELEMS/4
#define N_TOKENS 2048
#define F4       4096       // float4 per token
#define K_TOTAL  65536u     // K * B * S
#define NBINS    4096       // fine bins over key range [0xC0000000, 0xC1000000) == f in [2,8)
                            // bin width ~0.001 at cutoff => ~190 elems in cutoff bin

// ws layout (uint32 word indices)
#define C_NG       4096     // gated-list counter
#define C_WINTH    4097     // winner threshold (key >= -> definitely selected)
#define C_CANDTH   4098     // candidate threshold (cutoff-bin lower edge)
#define C_NEED     4099     // how many to take from the cutoff bin
#define C_FB       4100     // fallback flag
#define C_N2       4101     // cutoff-bin candidate counter
#define N_CTR_END  4160

#define GLIST_OFF  8192u    // uint2: all gated (f>=2) elements, (key, flat_idx)
#define CAPG       4194304u // expected ~380K; overflow -> fallback
#define LIST2_OFF  (GLIST_OFF + 2u*CAPG)
#define CAP2       4096u    // cutoff-bin candidates (expected ~190)
#define FB1_OFF    16777216u  // fallback scratch lists (correctness-only path)
#define CAPF       2097152u
#define FB2_OFF    (FB1_OFF + 2u*CAPF)

// Order-preserving fp32 -> u32 map (larger float <=> larger key)
__device__ __forceinline__ unsigned keyOf(float f) {
    unsigned b = __float_as_uint(f);
    return b ^ ((unsigned)((int)b >> 31) | 0x80000000u);
}
__device__ __forceinline__ float valOf(unsigned u) {
    unsigned b = (u & 0x80000000u) ? (u ^ 0x80000000u) : ~u;
    return __uint_as_float(b);
}
__device__ __forceinline__ unsigned umaxu(unsigned a, unsigned b) { return a > b ? a : b; }

// ---------------- init: zero fine bins + counters (no poison assumptions)
__global__ void k_init(unsigned* __restrict__ ws) {
    int t = blockIdx.x * 256 + threadIdx.x;
    if (t < N_CTR_END) ws[t] = 0u;
}

// ---------------- pass 1 (the ONLY full read of x): fine gated histogram
// + compact gated elements to global list + dense-zero this token's output.
#define GBUF 1024
__global__ __launch_bounds__(512) void k_hist(const float4* __restrict__ x,
                                              const int* __restrict__ mask,
                                              unsigned* __restrict__ ws,
                                              float4* __restrict__ out) {
    __shared__ unsigned lh[NBINS];     // 16 KB
    __shared__ uint2 sbuf[GBUF];       // 8 KB staging for compaction
    __shared__ unsigned s_cnt, s_base;
    const int tok = blockIdx.x;
    float4* ot = out + (size_t)tok * F4;
    const float4 z = make_float4(0.f, 0.f, 0.f, 0.f);
    if (!mask[tok]) {                  // masked token: zero output, no read
        for (int j = threadIdx.x; j < F4; j += 512) ot[j] = z;
        return;
    }
    for (int b = threadIdx.x; b < NBINS; b += 512) lh[b] = 0u;
    if (threadIdx.x == 0) s_cnt = 0u;
    __syncthreads();
    uint2* glist = (uint2*)(ws + GLIST_OFF);
    const float4* xt = x + (size_t)tok * F4;
    const unsigned baseIdx = (unsigned)tok * 16384u;
    for (int j = threadIdx.x; j < F4; j += 512) {
        float4 v = xt[j];
        ot[j] = z;                     // fused dense zero (winners overwritten later)
        float fv[4] = {v.x, v.y, v.z, v.w};
        #pragma unroll
        for (int c = 0; c < 4; c++) {
            float f = fv[c];
            if (f >= 2.0f) {           // ~2.3% of elements; cutoff ~2.66 for this input
                unsigned u = keyOf(f);
                unsigned bin = (u - 0xC0000000u) >> 12;
                if (bin > 4095u) bin = 4095u;      // f>=8 clamps to top bin
                atomicAdd(&lh[bin], 1u);
                unsigned slot = atomicAdd(&s_cnt, 1u);
                uint2 e = make_uint2(u, baseIdx + (unsigned)j * 4u + (unsigned)c);
                if (slot < GBUF) sbuf[slot] = e;
                else { unsigned g = atomicAdd(&ws[C_NG], 1u); if (g < CAPG) glist[g] = e; }
            }
        }
    }
    __syncthreads();
    for (int b = threadIdx.x; b < NBINS; b += 512) {
        unsigned c = lh[b];
        if (c) atomicAdd(&ws[b], c);   // ~350 nonzero bins/block
    }
    unsigned cnt = s_cnt; if (cnt > GBUF) cnt = GBUF;   // expected ~373/block
    if (threadIdx.x == 0) s_base = atomicAdd(&ws[C_NG], cnt);  // one bulk atomic/block
    __syncthreads();
    for (unsigned j = threadIdx.x; j < cnt; j += 512) {
        unsigned p = s_base + j;
        if (p < CAPG) glist[p] = sbuf[j];
    }
}

// ---------------- scan: suffix-scan 4096 fine bins -> thresholds, need, fallback flag
__global__ __launch_bounds__(1024) void k_scan1(unsigned* __restrict__ ws) {
    __shared__ unsigned sc[1024];
    __shared__ unsigned sB1, sKA, sFound;
    const int t = threadIdx.x;
    unsigned vv[4];
    unsigned s = 0u;
    #pragma unroll
    for (int j = 0; j < 4; ++j) { vv[j] = ws[t * 4 + j]; s += vv[j]; }
    if (t == 0) sFound = 0u;
    sc[t] = s;
    __syncthreads();
    for (int off = 1; off < 1024; off <<= 1) {
        unsigned a = sc[t];
        unsigned b = (t + off < 1024) ? sc[t + off] : 0u;
        __syncthreads();
        sc[t] = a + b;
        __syncthreads();
    }
    unsigned run = (t < 1023) ? sc[t + 1] : 0u;      // cntGE(first bin of next chunk)
    #pragma unroll
    for (int j = 3; j >= 0; --j) {
        unsigned prev = run; run += vv[j];           // run = cntGE(bin t*4+j)
        if (run >= K_TOTAL && prev < K_TOTAL) {      // unique crossing
            sB1 = (unsigned)(t * 4 + j); sKA = prev; sFound = 1u;
        }
    }
    __syncthreads();
    if (t == 0) {
        unsigned total = sc[0];
        unsigned ng = ws[C_NG];
        unsigned fb = (sFound == 0u) || (total < K_TOTAL) || (sB1 == 4095u) || (ng > CAPG);
        ws[C_FB] = fb ? 1u : 0u;
        if (!fb) {
            unsigned candTh = 0xC0000000u + (sB1 << 12);
            ws[C_CANDTH] = candTh;
            ws[C_WINTH]  = candTh + 0x1000u;
            ws[C_NEED]   = K_TOTAL - sKA;
        }
    }
}

// ---------------- scatter winners from the compact gated list (no x re-read);
// the zeroed lines are still cache-dirty -> these scattered writes hit L2/L3.
__global__ __launch_bounds__(256) void k_scatter(unsigned* __restrict__ ws,
                                                 float* __restrict__ out) {
    if (ws[C_FB]) return;
    const unsigned winTh = ws[C_WINTH], candTh = ws[C_CANDTH];
    unsigned ng = ws[C_NG]; if (ng > CAPG) ng = CAPG;
    uint2* glist = (uint2*)(ws + GLIST_OFF);
    uint2* list2 = (uint2*)(ws + LIST2_OFF);
    const unsigned stride = gridDim.x * 256;
    for (unsigned i = blockIdx.x * 256 + threadIdx.x; i < ng; i += stride) {
        uint2 e = glist[i];
        if (e.x >= winTh) out[e.y] = valOf(e.x);     // >= 2.0 > 0: relu moot
        else if (e.x >= candTh) {                    // cutoff bin (~190 total)
            unsigned g = atomicAdd(&ws[C_N2], 1u);
            if (g < CAP2) list2[g] = e;
        }
    }
}

// ---------------- tail: exact rank among ~190 cutoff-bin candidates + EMA threshold
__global__ __launch_bounds__(256) void k_tail(unsigned* __restrict__ ws,
                                              float* __restrict__ out,
                                              const float* __restrict__ thr) {
    if (ws[C_FB]) return;
    __shared__ uint2 ent[CAP2];        // 32 KB
    __shared__ unsigned sred[256];
    const int t = threadIdx.x;
    unsigned rawn2 = ws[C_N2];
    if (rawn2 > CAP2) { if (t == 0) ws[C_FB] = 1u; return; }   // hand off to fallback
    const unsigned n2 = rawn2;
    const unsigned need = ws[C_NEED];  // >= 1 by crossing construction
    uint2* list2 = (uint2*)(ws + LIST2_OFF);
    for (unsigned i = t; i < n2; i += 256) ent[i] = list2[i];
    __syncthreads();
    unsigned minSel = 0xFFFFFFFFu;
    for (unsigned i = t; i < n2; i += 256) {
        uint2 e = ent[i];
        unsigned rank = 0u;
        for (unsigned j = 0; j < n2; ++j) {          // ties -> lower idx (jax.lax.top_k)
            uint2 o = ent[j];
            rank += (o.x > e.x || (o.x == e.x && o.y < e.y)) ? 1u : 0u;
        }
        if (rank < need) {
            out[e.y] = valOf(e.x);
            if (e.x < minSel) minSel = e.x;
        }
    }
    sred[t] = minSel;
    __syncthreads();
    for (int off = 128; off > 0; off >>= 1) {
        if (t < off) sred[t] = sred[t] < sred[t + off] ? sred[t] : sred[t + off];
        __syncthreads();
    }
    if (t == 0) {
        // fast path: min selected = k-th largest >= 2.0 > 0 == min_pos
        out[N_ELEMS] = 0.99f * thr[0] + 0.01f * valOf(sred[0]);
    }
}

// ---------------- fallback: full exact algorithm, single block (correctness-only;
// never runs for this input — cutoff >= 2.0 with 5.8x margin)
__global__ __launch_bounds__(1024) void k_fallback(const float4* __restrict__ x,
                                                   const int* __restrict__ mask,
                                                   unsigned* __restrict__ ws,
                                                   float* __restrict__ out,
                                                   const float* __restrict__ thr) {
    if (ws[C_FB] == 0u) return;
    __shared__ unsigned lh[NBINS];     // 16 KB, coarse 12-bit bins then reused
    __shared__ unsigned sred[1024];
    __shared__ unsigned sB1, sKA, sMode, sNegmin, sB2, sNeed, sCnt;
    const int t = threadIdx.x;
    for (int b = t; b < NBINS; b += 1024) lh[b] = 0u;
    __syncthreads();
    unsigned negmin = 0u;              // max(~key) over positive values
    for (int tok = 0; tok < N_TOKENS; ++tok) {
        if (!mask[tok]) continue;
        const float4* xt = x + (size_t)tok * F4;
        for (int j = t; j < F4; j += 1024) {
            float4 v = xt[j];
            float fv[4] = {v.x, v.y, v.z, v.w};
            #pragma unroll
            for (int c = 0; c < 4; ++c) {
                float f = fv[c];
                unsigned u = keyOf(f);
                atomicAdd(&lh[u >> 20], 1u);
                if (f > 0.0f) negmin = umaxu(negmin, ~u);
            }
        }
    }
    __syncthreads();
    sred[t] = negmin; __syncthreads();
    for (int off = 512; off > 0; off >>= 1) {
        if (t < off) sred[t] = umaxu(sred[t], sred[t + off]);
        __syncthreads();
    }
    if (t == 0) {
        sNegmin = sred[0];
        unsigned tot = 0u;
        for (int b = 0; b < NBINS; ++b) tot += lh[b];
        if (tot <= K_TOTAL) sMode = 1u;          // select ALL unmasked elements
        else {
            sMode = 0u;
            unsigned run = 0u, prev = 0u; int b1 = 0;
            for (int b = NBINS - 1; b >= 0; --b) {
                prev = run; run += lh[b];
                if (run >= K_TOTAL && prev < K_TOTAL) { b1 = b; break; }
            }
            sB1 = (unsigned)b1; sKA = prev;
        }
        sCnt = 0u;
    }
    __syncthreads();
    if (sMode == 1u) {
        for (int tok = 0; tok < N_TOKENS; ++tok) {
            if (!mask[tok]) continue;
            const float4* xt = x + (size_t)tok * F4;
            float* ot = out + (size_t)tok * 16384;
            for (int j = t; j < F4; j += 1024) {
                float4 v = xt[j];
                ot[j * 4 + 0] = fmaxf(v.x, 0.f); ot[j * 4 + 1] = fmaxf(v.y, 0.f);
                ot[j * 4 + 2] = fmaxf(v.z, 0.f); ot[j * 4 + 3] = fmaxf(v.w, 0.f);
            }
        }
        if (t == 0) {
            float th = thr[0], newt = th;
            if (sNegmin) newt = 0.99f * th + 0.01f * valOf(~sNegmin);
            out[N_ELEMS] = newt;
        }
        return;
    }
    // phase 2: scatter coarse winners; compact coarse cutoff bin
    const unsigned B1c = sB1;
    uint2* fb1 = (uint2*)(ws + FB1_OFF);
    for (int tok = 0; tok < N_TOKENS; ++tok) {
        if (!mask[tok]) continue;
        const float4* xt = x + (size_t)tok * F4;
        const unsigned baseIdx = (unsigned)tok * 16384u;
        for (int j = t; j < F4; j += 1024) {
            float4 v = xt[j];
            float fv[4] = {v.x, v.y, v.z, v.w};
            #pragma unroll
            for (int c = 0; c < 4; ++c) {
                float f = fv[c];
                unsigned u = keyOf(f);
                unsigned p = u >> 20;
                unsigned idx = baseIdx + (unsigned)j * 4u + (unsigned)c;
                if (p > B1c) out[idx] = fmaxf(f, 0.f);
                else if (p == B1c) {
                    unsigned g = atomicAdd(&sCnt, 1u);
                    if (g < CAPF) fb1[g] = make_uint2(u, idx);
                }
            }
        }
    }
    __syncthreads();
    unsigned n1 = sCnt > CAPF ? CAPF : sCnt;
    __syncthreads();
    if (t < 256) lh[t] = 0u;           // reuse as 8-bit refine histogram
    if (t == 0) sCnt = 0u;
    __syncthreads();
    for (unsigned i = t; i < n1; i += 1024)
        atomicAdd(&lh[(fb1[i].x >> 12) & 255u], 1u);
    __syncthreads();
    if (t == 0) {
        unsigned run = sKA, prev = sKA; int b2 = 0;
        for (int b = 255; b >= 0; --b) {
            prev = run; run += lh[b];
            if (run >= K_TOTAL) { b2 = b; break; }
        }
        sB2 = (unsigned)b2; sNeed = K_TOTAL - prev;
    }
    __syncthreads();
    const unsigned B2 = sB2, need = sNeed;
    uint2* fb2 = (uint2*)(ws + FB2_OFF);
    for (unsigned i = t; i < n1; i += 1024) {
        uint2 e = fb1[i];
        unsigned bb = (e.x >> 12) & 255u;
        if (bb > B2) out[e.y] = fmaxf(valOf(e.x), 0.f);
        else if (bb == B2) {
            unsigned g = atomicAdd(&sCnt, 1u);
            if (g < CAPF) fb2[g] = e;
        }
    }
    __syncthreads();
    unsigned n2 = sCnt > CAPF ? CAPF : sCnt;
    unsigned minSel = 0xFFFFFFFFu;
    for (unsigned i = t; i < n2; i += 1024) {
        uint2 e = fb2[i];
        unsigned rank = 0u;
        for (unsigned jj = 0; jj < n2; ++jj) {
            uint2 o = fb2[jj];
            rank += (o.x > e.x || (o.x == e.x && o.y < e.y)) ? 1u : 0u;
        }
        if (rank < need) { out[e.y] = fmaxf(valOf(e.x), 0.f); if (e.x < minSel) minSel = e.x; }
    }
    __syncthreads();
    sred[t] = minSel; __syncthreads();
    for (int off = 512; off > 0; off >>= 1) {
        if (t < off) sred[t] = sred[t] < sred[t + off] ? sred[t] : sred[t + off];
        __syncthreads();
    }
    if (t == 0) {
        float th = thr[0], newt = th;
        unsigned vku = sred[0];
        if (vku != 0xFFFFFFFFu) {
            float vk = valOf(vku);
            float minpos; int any;
            if (vk > 0.f) { minpos = vk; any = 1; }
            else { any = (sNegmin != 0u); minpos = any ? valOf(~sNegmin) : 0.f; }
            if (any) newt = 0.99f * th + 0.01f * minpos;
        }
        out[N_ELEMS] = newt;
    }
}

extern "C" void kernel_launch(void* const* d_in, const int* in_sizes, int n_in,
                              void* d_out, int out_size, void* d_ws, size_t ws_size,
                              hipStream_t stream) {
    const float4* x  = (const float4*)d_in[0];
    const int* mask  = (const int*)d_in[1];
    const float* thr = (const float*)d_in[2];
    float* out       = (float*)d_out;
    unsigned* ws     = (unsigned*)d_ws;

    k_init    <<<17, 256, 0, stream>>>(ws);
    k_hist    <<<N_TOKENS, 512, 0, stream>>>(x, mask, ws, (float4*)out);
    k_scan1   <<<1, 1024, 0, stream>>>(ws);
    k_scatter <<<256, 256, 0, stream>>>(ws, out);
    k_tail    <<<1, 256, 0, stream>>>(ws, out, thr);
    k_fallback<<<1, 1024, 0, stream>>>(x, mask, ws, out, thr);
}